// Round 4
// baseline (361.704 us; speedup 1.0000x reference)
//
#include <hip/hip_runtime.h>
#include <stdint.h>

// MultiHeadAttention: x[4,2048,1024] fp32; Wq/Wk/Wv/Wo [1024,1024]; biases zero.
// out = softmax((xWq^T)(xWk^T)^T / 32) (xWv^T) Wo^T + bo   (16 heads, d=64)
//
// Pipeline (bf16 MFMA, fp32 accum):
//  k_cvt: x,W* fp32->bf16
//  k_gemm (global_load_lds width-16 staging, linear pow2 LDS, m97 recipe):
//    MODE_QK(scale=log2e/32): Q -> [bh][tok][64] (pre-scaled for exp2)
//    MODE_QK(scale=1):        K -> [bh][tok][64]
//    MODE_V:                  V -> [bh][64][tok] (transposed for PV B-frags)
//    MODE_OUT:                O @ Wo^T + bo -> fp32 d_out
//  k_attn: flash-style, swapped-S^T MFMA (P lane-local along kv), pow2 LDS
//    rows (128B) + XOR swizzle ((row&7)<<4) both-sides (rule 21: linear
//    global_load_lds dest + pre-swizzled source + swizzled reads),
//    setprio around MFMA, 32KB LDS -> 5 blocks/CU.

#define HID 1024
#define NH 16
#define HD 64
#define BB 4
#define SEQ 2048
#define MTOT (BB * SEQ) // 8192

typedef short bf16x8 __attribute__((ext_vector_type(8)));
typedef float f32x4 __attribute__((ext_vector_type(4)));

// swizzle: byte col within a 128B row, XORed by row&7 -> conflict-free b128
#define SWZ(row, cb) ((cb) ^ (((row) & 7) << 4))

#define GLDS(gp, lp) __builtin_amdgcn_global_load_lds( \
    (const __attribute__((address_space(1))) void*)(gp), \
    (__attribute__((address_space(3))) void*)(lp), 16, 0, 0)

static __device__ __forceinline__ unsigned short f2bf(float f) {
  unsigned u = __float_as_uint(f);
  u += 0x7fffu + ((u >> 16) & 1u); // RNE
  return (unsigned short)(u >> 16);
}

static __device__ __forceinline__ f32x4 mfma16(bf16x8 a, bf16x8 b, f32x4 c) {
  return __builtin_amdgcn_mfma_f32_16x16x32_bf16(a, b, c, 0, 0, 0);
}

// ---------------- fp32 -> bf16 convert ----------------
__global__ void k_cvt(const float* __restrict__ in, unsigned short* __restrict__ out, int n4) {
  int i = blockIdx.x * blockDim.x + threadIdx.x;
  if (i >= n4) return;
  float4 v = reinterpret_cast<const float4*>(in)[i];
  ushort4 o;
  o.x = f2bf(v.x); o.y = f2bf(v.y); o.z = f2bf(v.z); o.w = f2bf(v.w);
  reinterpret_cast<ushort4*>(out)[i] = o;
}

// ---------------- GEMM: C[8192,1024] = A[M,K] @ W[N,K]^T + bias ----------------
// 128x128 tile, BK=64, 4 waves (2x2). Staging via global_load_lds dwordx4 into
// LINEAR [128][64]-short LDS (m97 recipe; no pad, no swizzle at 2-phase).
#define MODE_QK 0
#define MODE_V 1
#define MODE_OUT 2

__global__ __launch_bounds__(256, 2) void k_gemm(
    const unsigned short* __restrict__ A,
    const unsigned short* __restrict__ W,
    const float* __restrict__ bias,
    void* __restrict__ Cout, int mode, float scale) {
  const int K = HID;
  __shared__ __align__(16) unsigned short sA[128 * 64];
  __shared__ __align__(16) unsigned short sB[128 * 64];
  const int m0 = blockIdx.x * 128;
  const int n0 = blockIdx.y * 128;
  const int tid = threadIdx.x;
  const int lane = tid & 63, wid = tid >> 6;
  const int wr = wid >> 1, wc = wid & 1;
  const int lr = lane & 15, lg = lane >> 4;

  f32x4 acc[4][4] = {};

  const unsigned short* gA = A + (size_t)m0 * K;
  const unsigned short* gW = W + (size_t)n0 * K;

  for (int kt = 0; kt < K; kt += 64) {
    // 1024 16B chunks per tile; chunk c: row=c>>3, col=(c&7)*8 shorts;
    // LDS dest linear byte c*16 (= wave-uniform base + lane*16).
#pragma unroll
    for (int i = 0; i < 4; ++i) {
      int c = tid + i * 256;
      int row = c >> 3, col = (c & 7) << 3;
      GLDS(gA + (size_t)row * K + kt + col, (char*)sA + (size_t)c * 16);
      GLDS(gW + (size_t)row * K + kt + col, (char*)sB + (size_t)c * 16);
    }
    __syncthreads(); // drains vmcnt(0): staged data visible
#pragma unroll
    for (int kk = 0; kk < 64; kk += 32) {
      bf16x8 a[4], b[4];
      const int co = kk + lg * 8;
#pragma unroll
      for (int m = 0; m < 4; ++m)
        a[m] = *reinterpret_cast<const bf16x8*>(sA + (wr * 64 + m * 16 + lr) * 64 + co);
#pragma unroll
      for (int n = 0; n < 4; ++n)
        b[n] = *reinterpret_cast<const bf16x8*>(sB + (wc * 64 + n * 16 + lr) * 64 + co);
      __builtin_amdgcn_s_setprio(1);
#pragma unroll
      for (int m = 0; m < 4; ++m)
#pragma unroll
        for (int n = 0; n < 4; ++n)
          acc[m][n] = mfma16(a[m], b[n], acc[m][n]);
      __builtin_amdgcn_s_setprio(0);
    }
    __syncthreads();
  }

  if (mode == MODE_OUT) {
    float* C = (float*)Cout;
#pragma unroll
    for (int m = 0; m < 4; ++m) {
      int row0 = m0 + wr * 64 + m * 16 + lg * 4;
#pragma unroll
      for (int n = 0; n < 4; ++n) {
        int col = n0 + wc * 64 + n * 16 + lr;
        float bv = bias[col];
#pragma unroll
        for (int r = 0; r < 4; ++r)
          C[(size_t)(row0 + r) * HID + col] = acc[m][n][r] + bv;
      }
    }
  } else if (mode == MODE_QK) {
    unsigned short* C = (unsigned short*)Cout;
#pragma unroll
    for (int m = 0; m < 4; ++m) {
      int row0 = m0 + wr * 64 + m * 16 + lg * 4;
      int b = row0 >> 11;
#pragma unroll
      for (int n = 0; n < 4; ++n) {
        int col = n0 + wc * 64 + n * 16 + lr;
        float bv = bias[col];
        int h = col >> 6, d = col & 63;
        size_t base = ((size_t)(b * NH + h) * SEQ) * HD + d;
#pragma unroll
        for (int r = 0; r < 4; ++r) {
          int tok = (row0 + r) & 2047;
          C[base + (size_t)tok * HD] = f2bf((acc[m][n][r] + bv) * scale);
        }
      }
    }
  } else {
    unsigned short* C = (unsigned short*)Cout;
#pragma unroll
    for (int m = 0; m < 4; ++m) {
      int row0 = m0 + wr * 64 + m * 16 + lg * 4;
      int b = row0 >> 11;
      int tok0 = row0 & 2047;
#pragma unroll
      for (int n = 0; n < 4; ++n) {
        int col = n0 + wc * 64 + n * 16 + lr;
        float bv = bias[col];
        int h = col >> 6, d = col & 63;
        ushort4 pk;
        pk.x = f2bf(acc[m][n][0] + bv);
        pk.y = f2bf(acc[m][n][1] + bv);
        pk.z = f2bf(acc[m][n][2] + bv);
        pk.w = f2bf(acc[m][n][3] + bv);
        *reinterpret_cast<ushort4*>(&C[((size_t)(b * NH + h) * HD + d) * SEQ + tok0]) = pk;
      }
    }
  }
}

// ---------------- attention ----------------
// grid (bh=64, qt=16); 4 waves; wave owns 32 q-rows. KVB=64.
// All LDS tiles: [rows][64 shorts] = 128B rows, XOR-swizzled ((row&7)<<4).
// Staging: global_load_lds with pre-swizzled SOURCE + linear dest (rule 21).
// S^T = mfma(K,Q): lane holds P[q=w*32+m*16+lr][kv=n*16+4lg+r] -> exp2,
// scalar den, cvt_pk pairs, one b64 swizzled write per (m,n). PV reads
// wave-private sP rows (no extra barrier). 2 barriers/tile.
#define KVB 64

__global__ __launch_bounds__(256, 5) void k_attn(
    const unsigned short* __restrict__ Qg,  // [64][2048][64]
    const unsigned short* __restrict__ Kg,  // [64][2048][64]
    const unsigned short* __restrict__ Vt,  // [64][64][2048]
    unsigned short* __restrict__ Og) {      // [8192][1024] bf16
  __shared__ __align__(16) unsigned short sP[128 * 64]; // 16KB (Q staged here first)
  __shared__ __align__(16) unsigned short sK[KVB * 64]; //  8KB
  __shared__ __align__(16) unsigned short sV[KVB * 64]; //  8KB

  const int bh = blockIdx.x;
  const int qt = blockIdx.y;
  const int tid = threadIdx.x;
  const int lane = tid & 63, wid = tid >> 6;
  const int lr = lane & 15, lg = lane >> 4;

  const unsigned short* Qh = Qg + ((size_t)bh * SEQ + (size_t)qt * 128) * HD;
  const unsigned short* Kh = Kg + (size_t)bh * SEQ * HD;
  const unsigned short* Vh = Vt + (size_t)bh * HD * SEQ;

  // stage Q tile (128 rows x 128B): linear dest byte c*16, source pre-swizzled
#pragma unroll
  for (int i = 0; i < 4; ++i) {
    int c = tid + i * 256;
    int row = c >> 3;
    int cbl = SWZ(row, (c & 7) << 4); // logical byte col for this linear slot
    GLDS(Qh + (size_t)row * HD + (cbl >> 1), (char*)sP + (size_t)c * 16);
  }
  __syncthreads();
  bf16x8 qb[2][2];
#pragma unroll
  for (int m = 0; m < 2; ++m)
#pragma unroll
    for (int kd = 0; kd < 2; ++kd) {
      int row = wid * 32 + m * 16 + lr;
      qb[m][kd] = *reinterpret_cast<const bf16x8*>(
          (const char*)sP + row * 128 + SWZ(lr, kd * 64 + lg * 16));
    }
  // safe: qb reads precede this thread's arrival at the first in-loop barrier;
  // sP is only rewritten (P-phase) after that barrier.

  f32x4 acco[2][4] = {};
  float denp[2] = {0.f, 0.f};

  for (int kt = 0; kt < SEQ; kt += KVB) {
    // stage K [64 kv][64 d] and V [64 d][64 kv] (source pre-swizzled)
#pragma unroll
    for (int i = 0; i < 2; ++i) {
      int c = tid + i * 256;
      int row = c >> 3;
      int cbl = SWZ(row, (c & 7) << 4);
      GLDS(Kh + (size_t)(kt + row) * HD + (cbl >> 1), (char*)sK + (size_t)c * 16);
      GLDS(Vh + (size_t)row * SEQ + kt + (cbl >> 1), (char*)sV + (size_t)c * 16);
    }
    __syncthreads(); // staged tiles visible (vmcnt+lgkm drained)

    // S^T = K Q^T : accs[m][n]: kv = n*16+4lg+r, q = wid*32+m*16+lr
    f32x4 accs[2][4] = {};
#pragma unroll
    for (int kd = 0; kd < 2; ++kd) {
#pragma unroll
      for (int n = 0; n < 4; ++n) {
        bf16x8 ka = *reinterpret_cast<const bf16x8*>(
            (const char*)sK + (n * 16 + lr) * 128 + SWZ(lr, kd * 64 + lg * 16));
        __builtin_amdgcn_s_setprio(1);
        accs[0][n] = mfma16(ka, qb[0][kd], accs[0][n]);
        accs[1][n] = mfma16(ka, qb[1][kd], accs[1][n]);
        __builtin_amdgcn_s_setprio(0);
      }
    }

    // P = exp2(S^T) -> den accum + packed bf16 swizzled b64 write to sP[q][kv]
#pragma unroll
    for (int m = 0; m < 2; ++m) {
      const int q = wid * 32 + m * 16 + lr;
#pragma unroll
      for (int n = 0; n < 4; ++n) {
        float p0 = exp2f(accs[m][n][0]);
        float p1 = exp2f(accs[m][n][1]);
        float p2 = exp2f(accs[m][n][2]);
        float p3 = exp2f(accs[m][n][3]);
        denp[m] += (p0 + p1) + (p2 + p3);
        unsigned w0, w1;
        asm("v_cvt_pk_bf16_f32 %0, %1, %2" : "=v"(w0) : "v"(p0), "v"(p1));
        asm("v_cvt_pk_bf16_f32 %0, %1, %2" : "=v"(w1) : "v"(p2), "v"(p3));
        uint2 pk; pk.x = w0; pk.y = w1;
        *reinterpret_cast<uint2*>((char*)sP + q * 128 + SWZ(q, n * 32 + lg * 8)) = pk;
      }
    }
    // no barrier: PV below reads only this wave's own sP rows.

    // O += P V
#pragma unroll
    for (int js = 0; js < 2; ++js) {
      bf16x8 pa[2], vb[4];
#pragma unroll
      for (int m = 0; m < 2; ++m) {
        int row = wid * 32 + m * 16 + lr;
        pa[m] = *reinterpret_cast<const bf16x8*>(
            (const char*)sP + row * 128 + SWZ(lr, js * 64 + lg * 16));
      }
#pragma unroll
      for (int n = 0; n < 4; ++n)
        vb[n] = *reinterpret_cast<const bf16x8*>(
            (const char*)sV + (n * 16 + lr) * 128 + SWZ(lr, js * 64 + lg * 16));
      __builtin_amdgcn_s_setprio(1);
#pragma unroll
      for (int m = 0; m < 2; ++m)
#pragma unroll
        for (int n = 0; n < 4; ++n)
          acco[m][n] = mfma16(pa[m], vb[n], acco[m][n]);
      __builtin_amdgcn_s_setprio(0);
    }
    __syncthreads(); // protect sK/sV/sP before next staging
  }

  // den: reduce across lg-lanes (same lr), broadcast to output rows
  float rden[2][4];
#pragma unroll
  for (int m = 0; m < 2; ++m) {
    float d = denp[m];
    d += __shfl_xor(d, 16);
    d += __shfl_xor(d, 32);
#pragma unroll
    for (int r = 0; r < 4; ++r)
      rden[m][r] = 1.0f / __shfl(d, lg * 4 + r);
  }

  const int b = bh >> 4, h = bh & 15;
#pragma unroll
  for (int m = 0; m < 2; ++m) {
    int tok0 = qt * 128 + wid * 32 + m * 16 + lg * 4;
#pragma unroll
    for (int n = 0; n < 4; ++n) {
      int col = h * 64 + n * 16 + lr;
#pragma unroll
      for (int r = 0; r < 4; ++r)
        Og[(size_t)(b * SEQ + tok0 + r) * HID + col] = f2bf(acco[m][n][r] * rden[m][r]);
    }
  }
}

// ---------------- launch ----------------
extern "C" void kernel_launch(void* const* d_in, const int* in_sizes, int n_in,
                              void* d_out, int out_size, void* d_ws, size_t ws_size,
                              hipStream_t stream) {
  (void)in_sizes; (void)n_in; (void)out_size; (void)ws_size;
  const float* x = (const float*)d_in[0];
  const float* Wq = (const float*)d_in[1];
  const float* bq = (const float*)d_in[2];
  const float* Wk = (const float*)d_in[3];
  const float* bk = (const float*)d_in[4];
  const float* Wv = (const float*)d_in[5];
  const float* bv = (const float*)d_in[6];
  const float* Wo = (const float*)d_in[7];
  const float* bo = (const float*)d_in[8];

  unsigned short* ws = (unsigned short*)d_ws;
  unsigned short* xb = ws;
  unsigned short* wqb = xb + (size_t)MTOT * HID;
  unsigned short* wkb = wqb + (size_t)HID * HID;
  unsigned short* wvb = wkb + (size_t)HID * HID;
  unsigned short* wob = wvb + (size_t)HID * HID;
  unsigned short* qb = wob + (size_t)HID * HID;   // [64][2048][64]
  unsigned short* kb = qb + (size_t)MTOT * HID;   // [64][2048][64]
  unsigned short* vtb = kb + (size_t)MTOT * HID;  // [64][64][2048]
  unsigned short* ob = vtb + (size_t)MTOT * HID;  // [8192][1024]

  const float cexp = 0.04508422f; // log2(e)/32

  k_cvt<<<(MTOT * HID / 4) / 256, 256, 0, stream>>>(x, xb, MTOT * HID / 4);
  k_cvt<<<(HID * HID / 4) / 256, 256, 0, stream>>>(Wq, wqb, HID * HID / 4);
  k_cvt<<<(HID * HID / 4) / 256, 256, 0, stream>>>(Wk, wkb, HID * HID / 4);
  k_cvt<<<(HID * HID / 4) / 256, 256, 0, stream>>>(Wv, wvb, HID * HID / 4);
  k_cvt<<<(HID * HID / 4) / 256, 256, 0, stream>>>(Wo, wob, HID * HID / 4);

  dim3 gg(MTOT / 128, HID / 128); // 64 x 8
  k_gemm<<<gg, 256, 0, stream>>>(xb, wqb, bq, qb, MODE_QK, cexp);
  k_gemm<<<gg, 256, 0, stream>>>(xb, wkb, bk, kb, MODE_QK, 1.0f);
  k_gemm<<<gg, 256, 0, stream>>>(xb, wvb, bv, vtb, MODE_V, 1.0f);

  k_attn<<<dim3(64, SEQ / 128), 256, 0, stream>>>(qb, kb, vtb, ob);

  k_gemm<<<gg, 256, 0, stream>>>(ob, wob, bo, d_out, MODE_OUT, 1.0f);
}

// Round 5
// 239.741 us; speedup vs baseline: 1.5087x; 1.5087x over previous
//
#include <hip/hip_runtime.h>
#include <stdint.h>

// MultiHeadAttention: x[4,2048,1024] fp32; Wq/Wk/Wv/Wo [1024,1024]; biases zero.
// out = softmax((xWq^T)(xWk^T)^T / 32) (xWv^T) Wo^T + bo   (16 heads, d=64)
//
// Pipeline (bf16 MFMA, fp32 accum):
//  k_cvt: x,W* fp32->bf16
//  k_gemm (global_load_lds width-16 staging, linear pow2 LDS, m97 recipe)
//  k_attn: flash-style, swapped-S^T MFMA (P lane-local along kv), 128B LDS
//    rows + XOR swizzle ((row&7)<<4) both-sides, 32KB LDS.
//    launch_bounds(256,4): r4 lesson — (256,5) squeezed VGPR to 96 and
//    spilled accumulators to scratch (675MB writes, 2x slower).

#define HID 1024
#define NH 16
#define HD 64
#define BB 4
#define SEQ 2048
#define MTOT (BB * SEQ) // 8192

typedef short bf16x8 __attribute__((ext_vector_type(8)));
typedef float f32x4 __attribute__((ext_vector_type(4)));

// swizzle: byte col within a 128B row, XORed by row&7 -> conflict-free b128
#define SWZ(row, cb) ((cb) ^ (((row) & 7) << 4))

#define GLDS(gp, lp) __builtin_amdgcn_global_load_lds( \
    (const __attribute__((address_space(1))) void*)(gp), \
    (__attribute__((address_space(3))) void*)(lp), 16, 0, 0)

static __device__ __forceinline__ unsigned short f2bf(float f) {
  unsigned u = __float_as_uint(f);
  u += 0x7fffu + ((u >> 16) & 1u); // RNE
  return (unsigned short)(u >> 16);
}

static __device__ __forceinline__ f32x4 mfma16(bf16x8 a, bf16x8 b, f32x4 c) {
  return __builtin_amdgcn_mfma_f32_16x16x32_bf16(a, b, c, 0, 0, 0);
}

// ---------------- fp32 -> bf16 convert ----------------
__global__ void k_cvt(const float* __restrict__ in, unsigned short* __restrict__ out, int n4) {
  int i = blockIdx.x * blockDim.x + threadIdx.x;
  if (i >= n4) return;
  float4 v = reinterpret_cast<const float4*>(in)[i];
  ushort4 o;
  o.x = f2bf(v.x); o.y = f2bf(v.y); o.z = f2bf(v.z); o.w = f2bf(v.w);
  reinterpret_cast<ushort4*>(out)[i] = o;
}

// ---------------- GEMM: C[8192,1024] = A[M,K] @ W[N,K]^T + bias ----------------
// 128x128 tile, BK=64, 4 waves (2x2). global_load_lds dwordx4 into LINEAR
// [128][64]-short LDS (m97 recipe).
#define MODE_QK 0
#define MODE_V 1
#define MODE_OUT 2

__global__ __launch_bounds__(256, 2) void k_gemm(
    const unsigned short* __restrict__ A,
    const unsigned short* __restrict__ W,
    const float* __restrict__ bias,
    void* __restrict__ Cout, int mode, float scale) {
  const int K = HID;
  __shared__ __align__(16) unsigned short sA[128 * 64];
  __shared__ __align__(16) unsigned short sB[128 * 64];
  const int m0 = blockIdx.x * 128;
  const int n0 = blockIdx.y * 128;
  const int tid = threadIdx.x;
  const int lane = tid & 63, wid = tid >> 6;
  const int wr = wid >> 1, wc = wid & 1;
  const int lr = lane & 15, lg = lane >> 4;

  f32x4 acc[4][4] = {};

  const unsigned short* gA = A + (size_t)m0 * K;
  const unsigned short* gW = W + (size_t)n0 * K;

  for (int kt = 0; kt < K; kt += 64) {
#pragma unroll
    for (int i = 0; i < 4; ++i) {
      int c = tid + i * 256;
      int row = c >> 3, col = (c & 7) << 3;
      GLDS(gA + (size_t)row * K + kt + col, (char*)sA + (size_t)c * 16);
      GLDS(gW + (size_t)row * K + kt + col, (char*)sB + (size_t)c * 16);
    }
    __syncthreads(); // drains vmcnt(0): staged data visible
#pragma unroll
    for (int kk = 0; kk < 64; kk += 32) {
      bf16x8 a[4], b[4];
      const int co = kk + lg * 8;
#pragma unroll
      for (int m = 0; m < 4; ++m)
        a[m] = *reinterpret_cast<const bf16x8*>(sA + (wr * 64 + m * 16 + lr) * 64 + co);
#pragma unroll
      for (int n = 0; n < 4; ++n)
        b[n] = *reinterpret_cast<const bf16x8*>(sB + (wc * 64 + n * 16 + lr) * 64 + co);
      __builtin_amdgcn_s_setprio(1);
#pragma unroll
      for (int m = 0; m < 4; ++m)
#pragma unroll
        for (int n = 0; n < 4; ++n)
          acc[m][n] = mfma16(a[m], b[n], acc[m][n]);
      __builtin_amdgcn_s_setprio(0);
    }
    __syncthreads();
  }

  if (mode == MODE_OUT) {
    float* C = (float*)Cout;
#pragma unroll
    for (int m = 0; m < 4; ++m) {
      int row0 = m0 + wr * 64 + m * 16 + lg * 4;
#pragma unroll
      for (int n = 0; n < 4; ++n) {
        int col = n0 + wc * 64 + n * 16 + lr;
        float bv = bias[col];
#pragma unroll
        for (int r = 0; r < 4; ++r)
          C[(size_t)(row0 + r) * HID + col] = acc[m][n][r] + bv;
      }
    }
  } else if (mode == MODE_QK) {
    unsigned short* C = (unsigned short*)Cout;
#pragma unroll
    for (int m = 0; m < 4; ++m) {
      int row0 = m0 + wr * 64 + m * 16 + lg * 4;
      int b = row0 >> 11;
#pragma unroll
      for (int n = 0; n < 4; ++n) {
        int col = n0 + wc * 64 + n * 16 + lr;
        float bv = bias[col];
        int h = col >> 6, d = col & 63;
        size_t base = ((size_t)(b * NH + h) * SEQ) * HD + d;
#pragma unroll
        for (int r = 0; r < 4; ++r) {
          int tok = (row0 + r) & 2047;
          C[base + (size_t)tok * HD] = f2bf((acc[m][n][r] + bv) * scale);
        }
      }
    }
  } else {
    unsigned short* C = (unsigned short*)Cout;
#pragma unroll
    for (int m = 0; m < 4; ++m) {
      int row0 = m0 + wr * 64 + m * 16 + lg * 4;
      int b = row0 >> 11;
      int tok0 = row0 & 2047;
#pragma unroll
      for (int n = 0; n < 4; ++n) {
        int col = n0 + wc * 64 + n * 16 + lr;
        float bv = bias[col];
        int h = col >> 6, d = col & 63;
        ushort4 pk;
        pk.x = f2bf(acc[m][n][0] + bv);
        pk.y = f2bf(acc[m][n][1] + bv);
        pk.z = f2bf(acc[m][n][2] + bv);
        pk.w = f2bf(acc[m][n][3] + bv);
        *reinterpret_cast<ushort4*>(&C[((size_t)(b * NH + h) * HD + d) * SEQ + tok0]) = pk;
      }
    }
  }
}

// ---------------- attention ----------------
// grid (bh=64, qt=16); 4 waves; wave owns 32 q-rows. KVB=64.
// All LDS tiles: [rows][64 shorts] = 128B rows, XOR-swizzled ((row&7)<<4).
// Staging: global_load_lds, linear dest + pre-swizzled source (rule 21).
// S^T = mfma(K,Q): lane holds P[q=w*32+m*16+lr][kv=n*16+4lg+r] -> exp2,
// scalar den, cvt_pk pairs, one b64 swizzled write per (m,n). PV reads
// wave-private sP rows (no extra barrier). 2 barriers/tile.
#define KVB 64

__global__ __launch_bounds__(256, 4) void k_attn(
    const unsigned short* __restrict__ Qg,  // [64][2048][64]
    const unsigned short* __restrict__ Kg,  // [64][2048][64]
    const unsigned short* __restrict__ Vt,  // [64][64][2048]
    unsigned short* __restrict__ Og) {      // [8192][1024] bf16
  __shared__ __align__(16) unsigned short sP[128 * 64]; // 16KB (Q staged here first)
  __shared__ __align__(16) unsigned short sK[KVB * 64]; //  8KB
  __shared__ __align__(16) unsigned short sV[KVB * 64]; //  8KB

  const int bh = blockIdx.x;
  const int qt = blockIdx.y;
  const int tid = threadIdx.x;
  const int lane = tid & 63, wid = tid >> 6;
  const int lr = lane & 15, lg = lane >> 4;

  const unsigned short* Qh = Qg + ((size_t)bh * SEQ + (size_t)qt * 128) * HD;
  const unsigned short* Kh = Kg + (size_t)bh * SEQ * HD;
  const unsigned short* Vh = Vt + (size_t)bh * HD * SEQ;

  // stage Q tile (128 rows x 128B): linear dest byte c*16, source pre-swizzled
#pragma unroll
  for (int i = 0; i < 4; ++i) {
    int c = tid + i * 256;
    int row = c >> 3;
    int cbl = SWZ(row, (c & 7) << 4); // logical byte col for this linear slot
    GLDS(Qh + (size_t)row * HD + (cbl >> 1), (char*)sP + (size_t)c * 16);
  }
  __syncthreads();
  bf16x8 qb[2][2];
#pragma unroll
  for (int m = 0; m < 2; ++m)
#pragma unroll
    for (int kd = 0; kd < 2; ++kd) {
      int row = wid * 32 + m * 16 + lr;
      qb[m][kd] = *reinterpret_cast<const bf16x8*>(
          (const char*)sP + row * 128 + SWZ(lr, kd * 64 + lg * 16));
    }
  // safe: qb reads precede this thread's arrival at the first in-loop barrier;
  // sP is only rewritten (P-phase) after that barrier.

  f32x4 acco[2][4] = {};
  float denp[2] = {0.f, 0.f};

  for (int kt = 0; kt < SEQ; kt += KVB) {
    // stage K [64 kv][64 d] and V [64 d][64 kv] (source pre-swizzled)
#pragma unroll
    for (int i = 0; i < 2; ++i) {
      int c = tid + i * 256;
      int row = c >> 3;
      int cbl = SWZ(row, (c & 7) << 4);
      GLDS(Kh + (size_t)(kt + row) * HD + (cbl >> 1), (char*)sK + (size_t)c * 16);
      GLDS(Vh + (size_t)row * SEQ + kt + (cbl >> 1), (char*)sV + (size_t)c * 16);
    }
    __syncthreads(); // staged tiles visible (vmcnt+lgkm drained)

    // S^T = K Q^T : accs[m][n]: kv = n*16+4lg+r, q = wid*32+m*16+lr
    f32x4 accs[2][4] = {};
#pragma unroll
    for (int kd = 0; kd < 2; ++kd) {
      bf16x8 ka[4];
#pragma unroll
      for (int n = 0; n < 4; ++n)
        ka[n] = *reinterpret_cast<const bf16x8*>(
            (const char*)sK + (n * 16 + lr) * 128 + SWZ(lr, kd * 64 + lg * 16));
      __builtin_amdgcn_s_setprio(1);
#pragma unroll
      for (int n = 0; n < 4; ++n) {
        accs[0][n] = mfma16(ka[n], qb[0][kd], accs[0][n]);
        accs[1][n] = mfma16(ka[n], qb[1][kd], accs[1][n]);
      }
      __builtin_amdgcn_s_setprio(0);
    }

    // P = exp2(S^T) -> den accum + packed bf16 swizzled b64 write to sP[q][kv]
#pragma unroll
    for (int m = 0; m < 2; ++m) {
      const int q = wid * 32 + m * 16 + lr;
#pragma unroll
      for (int n = 0; n < 4; ++n) {
        float p0 = exp2f(accs[m][n][0]);
        float p1 = exp2f(accs[m][n][1]);
        float p2 = exp2f(accs[m][n][2]);
        float p3 = exp2f(accs[m][n][3]);
        denp[m] += (p0 + p1) + (p2 + p3);
        unsigned w0, w1;
        asm("v_cvt_pk_bf16_f32 %0, %1, %2" : "=v"(w0) : "v"(p0), "v"(p1));
        asm("v_cvt_pk_bf16_f32 %0, %1, %2" : "=v"(w1) : "v"(p2), "v"(p3));
        uint2 pk; pk.x = w0; pk.y = w1;
        *reinterpret_cast<uint2*>((char*)sP + q * 128 + SWZ(q, n * 32 + lg * 8)) = pk;
      }
    }
    // no barrier: PV below reads only this wave's own sP rows.

    // O += P V
#pragma unroll
    for (int js = 0; js < 2; ++js) {
      bf16x8 pa[2], vb[4];
#pragma unroll
      for (int m = 0; m < 2; ++m) {
        int row = wid * 32 + m * 16 + lr;
        pa[m] = *reinterpret_cast<const bf16x8*>(
            (const char*)sP + row * 128 + SWZ(lr, js * 64 + lg * 16));
      }
#pragma unroll
      for (int n = 0; n < 4; ++n)
        vb[n] = *reinterpret_cast<const bf16x8*>(
            (const char*)sV + (n * 16 + lr) * 128 + SWZ(lr, js * 64 + lg * 16));
      __builtin_amdgcn_s_setprio(1);
#pragma unroll
      for (int m = 0; m < 2; ++m)
#pragma unroll
        for (int n = 0; n < 4; ++n)
          acco[m][n] = mfma16(pa[m], vb[n], acco[m][n]);
      __builtin_amdgcn_s_setprio(0);
    }
    __syncthreads(); // protect sK/sV/sP before next staging
  }

  // den: reduce across lg-lanes (same lr), broadcast to output rows
  float rden[2][4];
#pragma unroll
  for (int m = 0; m < 2; ++m) {
    float d = denp[m];
    d += __shfl_xor(d, 16);
    d += __shfl_xor(d, 32);
#pragma unroll
    for (int r = 0; r < 4; ++r)
      rden[m][r] = 1.0f / __shfl(d, lg * 4 + r);
  }

  const int b = bh >> 4, h = bh & 15;
#pragma unroll
  for (int m = 0; m < 2; ++m) {
    int tok0 = qt * 128 + wid * 32 + m * 16 + lg * 4;
#pragma unroll
    for (int n = 0; n < 4; ++n) {
      int col = h * 64 + n * 16 + lr;
#pragma unroll
      for (int r = 0; r < 4; ++r)
        Og[(size_t)(b * SEQ + tok0 + r) * HID + col] = f2bf(acco[m][n][r] * rden[m][r]);
    }
  }
}

// ---------------- launch ----------------
extern "C" void kernel_launch(void* const* d_in, const int* in_sizes, int n_in,
                              void* d_out, int out_size, void* d_ws, size_t ws_size,
                              hipStream_t stream) {
  (void)in_sizes; (void)n_in; (void)out_size; (void)ws_size;
  const float* x = (const float*)d_in[0];
  const float* Wq = (const float*)d_in[1];
  const float* bq = (const float*)d_in[2];
  const float* Wk = (const float*)d_in[3];
  const float* bk = (const float*)d_in[4];
  const float* Wv = (const float*)d_in[5];
  const float* bv = (const float*)d_in[6];
  const float* Wo = (const float*)d_in[7];
  const float* bo = (const float*)d_in[8];

  unsigned short* ws = (unsigned short*)d_ws;
  unsigned short* xb = ws;
  unsigned short* wqb = xb + (size_t)MTOT * HID;
  unsigned short* wkb = wqb + (size_t)HID * HID;
  unsigned short* wvb = wkb + (size_t)HID * HID;
  unsigned short* wob = wvb + (size_t)HID * HID;
  unsigned short* qb = wob + (size_t)HID * HID;   // [64][2048][64]
  unsigned short* kb = qb + (size_t)MTOT * HID;   // [64][2048][64]
  unsigned short* vtb = kb + (size_t)MTOT * HID;  // [64][64][2048]
  unsigned short* ob = vtb + (size_t)MTOT * HID;  // [8192][1024]

  const float cexp = 0.04508422f; // log2(e)/32

  k_cvt<<<(MTOT * HID / 4) / 256, 256, 0, stream>>>(x, xb, MTOT * HID / 4);
  k_cvt<<<(HID * HID / 4) / 256, 256, 0, stream>>>(Wq, wqb, HID * HID / 4);
  k_cvt<<<(HID * HID / 4) / 256, 256, 0, stream>>>(Wk, wkb, HID * HID / 4);
  k_cvt<<<(HID * HID / 4) / 256, 256, 0, stream>>>(Wv, wvb, HID * HID / 4);
  k_cvt<<<(HID * HID / 4) / 256, 256, 0, stream>>>(Wo, wob, HID * HID / 4);

  dim3 gg(MTOT / 128, HID / 128); // 64 x 8
  k_gemm<<<gg, 256, 0, stream>>>(xb, wqb, bq, qb, MODE_QK, cexp);
  k_gemm<<<gg, 256, 0, stream>>>(xb, wkb, bk, kb, MODE_QK, 1.0f);
  k_gemm<<<gg, 256, 0, stream>>>(xb, wvb, bv, vtb, MODE_V, 1.0f);

  k_attn<<<dim3(64, SEQ / 128), 256, 0, stream>>>(qb, kb, vtb, ob);

  k_gemm<<<gg, 256, 0, stream>>>(ob, wob, bo, d_out, MODE_OUT, 1.0f);
}